// Round 11
// baseline (561.157 us; speedup 1.0000x reference)
//
#include <hip/hip_runtime.h>
#include <hip/hip_bf16.h>
#include <math.h>

// ---------------- problem constants ----------------
#define BATCH   4096
#define CH      64          // latent channels
#define KCB     512         // codebook size

// d_out layout (floats): x_tilde [4096,1,28,28], z_e_x [4096,64,7,7], z_q_x [4096,64,7,7]
#define XT_N    (BATCH*784)
#define ZE_OFF  (XT_N)
#define ZQ_OFF  (XT_N + BATCH*3136)

// workspace layout (bytes) — c1/c2 bf16
#define WS_C1   0
#define WS_C2   51380224ULL
#define WS_ST   154140672ULL            // stats: double sum1[32] sq1[32] sum2[16] sq2[16]
#define WS_WF2  154141824ULL            // w2 MFMA frags bf16: 16 KiB
#define WS_EF   154158208ULL            // codebook hi/lo MFMA frags: 128 KiB
#define WS_EE   154289280ULL            // ee[512] fp32 (fp64-accurate ||e||^2)
#define WS_WF1  WS_C2                   // w1 frags, clobbered later by c2 writes (stream order)

typedef __attribute__((ext_vector_type(8))) __bf16 bf16x8;
typedef __attribute__((ext_vector_type(4))) float f32x4;
union B8 { uint4 u; bf16x8 v; };

__device__ inline unsigned short f2bf(float f) {   // RNE fp32->bf16
    unsigned int u = __float_as_uint(f);
    u = u + 0x7fffu + ((u >> 16) & 1u);
    return (unsigned short)(u >> 16);
}
__device__ inline float bf2f(unsigned short h) {
    return __uint_as_float(((unsigned int)h) << 16);
}

// ---------------- prep: pack weights + codebook into per-lane MFMA fragments --------
// FROZEN (r9/r10). Slot rule shared by A and B: lane l, elem i -> k = kbase + 8*(l>>4) + i.
__global__ void k_prep(const float* __restrict__ w1, const float* __restrict__ w2,
                       const float* __restrict__ emb,
                       unsigned short* __restrict__ w1f, unsigned short* __restrict__ w2f,
                       unsigned short* __restrict__ ef, float* __restrict__ eeW,
                       double* __restrict__ stats) {
    int t = threadIdx.x + blockIdx.x * 256;     // 0..65535
    if (t < 96) stats[t] = 0.0;
    {   // codebook hi/lo fragments
        int i = t & 7, lane = (t >> 3) & 63, frag = t >> 9;       // frag 0..127
        int mt = frag >> 2, khalf = (frag >> 1) & 1, hilo = frag & 1;
        int cw = mt * 16 + (lane & 15);
        int k  = khalf * 32 + ((lane >> 4) << 3) + i;
        float v = emb[(cw << 6) + k];
        unsigned short h = f2bf(v);
        ef[t] = hilo ? f2bf(v - bf2f(h)) : h;
    }
    if (t < 32768) {
        int i = t & 7, lane = (t >> 3) & 63, frag = t >> 9;
        int cls = frag >> 4, tap = (frag >> 2) & 3, khalf = (frag >> 1) & 1, mt = frag & 1;
        int ph = cls >> 1, pw = cls & 1, dh = tap >> 1, dw = tap & 1;
        int kh = (1 - ph) + 2 * dh, kw = (1 - pw) + 2 * dw;
        int oc = mt * 16 + (lane & 15);
        int ic = khalf * 32 + ((lane >> 4) << 3) + i;
        w1f[t] = f2bf(w1[((ic * 32 + oc) << 4) + kh * 4 + kw]);
    }
    if (t < 8192) {
        int i = t & 7, lane = (t >> 3) & 63, frag = t >> 9;   // frag < 16
        int cls = frag >> 2, tap = frag & 3;
        int ph = cls >> 1, pw = cls & 1, dh = tap >> 1, dw = tap & 1;
        int kh = (1 - ph) + 2 * dh, kw = (1 - pw) + 2 * dw;
        int oc = lane & 15;
        int ic = ((lane >> 4) << 3) + i;
        w2f[t] = f2bf(w2[((ic * 16 + oc) << 4) + kh * 4 + kw]);
    }
    if (t < KCB) {
        double s = 0.0;
        const float* e = emb + (t << 6);
        for (int c = 0; c < CH; ++c) s += (double)e[c] * (double)e[c];
        eeW[t] = (float)s;
    }
}

// ---------------- K1: gather + VQ argmin via split-bf16 MFMA + z_e_x/z_q_x ----------
// r10 structure + top-2 chains split by mt parity (4 independent chains -> half the
// sequential dep latency), exact merge with index tiebreak.
__global__ __launch_bounds__(256) void k1_encode(
    const int* __restrict__ xidx, const float* __restrict__ encW,
    const float* __restrict__ emb, const unsigned short* __restrict__ ef,
    const float* __restrict__ eeW, float* __restrict__ out)
{
    __shared__ __align__(16) unsigned short zh_s[98*72];
    __shared__ __align__(16) unsigned short zl_s[98*72];
    __shared__ float ee_s[KCB];

    const int tid = threadIdx.x, wave = tid >> 6, lane = tid & 63;
    const int b0 = blockIdx.x << 1;

    for (int k = tid; k < KCB; k += 256) ee_s[k] = eeW[k];

    {
        const long long r0 = xidx[b0], r1 = xidx[b0 + 1];
        const float4* src0 = (const float4*)(encW + r0*3136);
        const float4* src1 = (const float4*)(encW + r1*3136);
        float4* ze = (float4*)(out + ZE_OFF + (long long)b0*3136);
        for (int i = tid; i < 1568; i += 256) {
            float4 v = (i < 784) ? src0[i] : src1[i - 784];
            ze[i] = v;
            float vv[4] = {v.x, v.y, v.z, v.w};
            int base = i << 2;
            #pragma unroll
            for (int j = 0; j < 4; ++j) {
                int idx = base + j;               // 0..6271 over [img][c][hw]
                int img = idx >= 3136;
                int e   = idx - img*3136;
                int c   = e / 49, hw = e - c*49;
                int pos = img*49 + hw;
                unsigned short hb = f2bf(vv[j]);
                zh_s[pos*72 + c] = hb;
                zl_s[pos*72 + c] = f2bf(vv[j] - bf2f(hb));
            }
        }
    }
    __syncthreads();

    const int col = lane & 15, g = lane >> 4;
    B8 Bh[2][2], Bl[2][2];
    #pragma unroll
    for (int t2 = 0; t2 < 2; ++t2) {
        int pos  = (wave*2 + t2)*16 + col;
        int posc = pos < 98 ? pos : 97;
        #pragma unroll
        for (int kh = 0; kh < 2; ++kh) {
            Bh[t2][kh].u = *(const uint4*)(zh_s + posc*72 + kh*32 + g*8);
            Bl[t2][kh].u = *(const uint4*)(zl_s + posc*72 + kh*32 + g*8);
        }
    }

    // 4 independent top-2 chains: [t2][mt&1]
    float d0[2][2], d1[2][2];
    int   k0[2][2], k1i[2][2];
    #pragma unroll
    for (int t2 = 0; t2 < 2; ++t2)
        #pragma unroll
        for (int p2 = 0; p2 < 2; ++p2) {
            d0[t2][p2] = 3.4e38f; d1[t2][p2] = 3.4e38f;
            k0[t2][p2] = 0;       k1i[t2][p2] = 1;
        }

    const uint4* ap = (const uint4*)ef + lane;
    uint4 A0 = ap[0*64], A1 = ap[1*64], A2 = ap[2*64], A3 = ap[3*64];

    for (int mt = 0; mt < 32; ++mt) {
        const int par = mt & 1;
        B8 Ah0, Al0, Ah1, Al1;
        Ah0.u = A0; Al0.u = A1; Ah1.u = A2; Al1.u = A3;
        if (mt < 31) {
            const uint4* np = ap + (mt+1)*256;
            A0 = np[0]; A1 = np[64]; A2 = np[128]; A3 = np[192];
        }
        const float4 eev = *(const float4*)&ee_s[mt*16 + (g << 2)];
        #pragma unroll
        for (int t2 = 0; t2 < 2; ++t2) {
            f32x4 acc = {eev.x*-0.5f, eev.y*-0.5f, eev.z*-0.5f, eev.w*-0.5f};
            acc = __builtin_amdgcn_mfma_f32_16x16x32_bf16(Ah0.v, Bh[t2][0].v, acc, 0,0,0);
            acc = __builtin_amdgcn_mfma_f32_16x16x32_bf16(Ah1.v, Bh[t2][1].v, acc, 0,0,0);
            acc = __builtin_amdgcn_mfma_f32_16x16x32_bf16(Ah0.v, Bl[t2][0].v, acc, 0,0,0);
            acc = __builtin_amdgcn_mfma_f32_16x16x32_bf16(Ah1.v, Bl[t2][1].v, acc, 0,0,0);
            acc = __builtin_amdgcn_mfma_f32_16x16x32_bf16(Al0.v, Bh[t2][0].v, acc, 0,0,0);
            acc = __builtin_amdgcn_mfma_f32_16x16x32_bf16(Al1.v, Bh[t2][1].v, acc, 0,0,0);
            acc = __builtin_amdgcn_mfma_f32_16x16x32_bf16(Al0.v, Bl[t2][0].v, acc, 0,0,0);
            acc = __builtin_amdgcn_mfma_f32_16x16x32_bf16(Al1.v, Bl[t2][1].v, acc, 0,0,0);
            #pragma unroll
            for (int rg = 0; rg < 4; ++rg) {
                float s = -2.f * acc[rg];
                int  cw = mt*16 + (g << 2) + rg;
                if (s < d0[t2][par] || (s == d0[t2][par] && cw < k0[t2][par])) {
                    d1[t2][par] = d0[t2][par]; k1i[t2][par] = k0[t2][par];
                    d0[t2][par] = s;           k0[t2][par] = cw;
                } else if (s < d1[t2][par] || (s == d1[t2][par] && cw < k1i[t2][par])) {
                    d1[t2][par] = s; k1i[t2][par] = cw;
                }
            }
        }
    }

    #pragma unroll
    for (int t2 = 0; t2 < 2; ++t2) {
        // merge the two parity chains (exact, index tiebreak)
        float a0v = d0[t2][0], a1v = d1[t2][0]; int ia0 = k0[t2][0], ia1 = k1i[t2][0];
        float b0v = d0[t2][1], b1v = d1[t2][1]; int ib0 = k0[t2][1], ib1 = k1i[t2][1];
        bool bf2 = (b0v < a0v) || (b0v == a0v && ib0 < ia0);
        float M0 = bf2 ? b0v : a0v; int Mi0 = bf2 ? ib0 : ia0;
        float ca = bf2 ? a0v : a1v; int ica = bf2 ? ia0 : ia1;
        float cb = bf2 ? b1v : b0v; int icb = bf2 ? ib1 : ib0;
        bool bs = (cb < ca) || (cb == ca && icb < ica);
        float M1 = bs ? cb : ca;   int Mi1 = bs ? icb : ica;

        // cross-lane merge (xor 16, 32)
        #pragma unroll
        for (int msk = 16; msk <= 32; msk <<= 1) {
            float e0 = __shfl_xor(M0, msk), e1 = __shfl_xor(M1, msk);
            int   j0 = __shfl_xor(Mi0, msk), j1 = __shfl_xor(Mi1, msk);
            if (e0 < M0 || (e0 == M0 && j0 < Mi0)) {
                if (M0 < e1 || (M0 == e1 && Mi0 < j1)) { M1 = M0; Mi1 = Mi0; }
                else                                    { M1 = e1; Mi1 = j1; }
                M0 = e0; Mi0 = j0;
            } else {
                if (e0 < M1 || (e0 == M1 && j0 < Mi1)) { M1 = e0; Mi1 = j0; }
            }
        }

        const int pos = (wave*2 + t2)*16 + col;
        if (pos < 98) {
            const int img = pos >= 49;
            const int b   = b0 + img;
            const int hw  = pos - img*49;
            int win = Mi0;

            // fp64 refine of near-ties from true fp32 z (engages rarely at 5e-6)
            if (M1 - M0 < 5e-6f) {
                const float* zp = out + ZE_OFF + (long long)b*3136 + hw;
                const float* ea = emb + Mi0*CH;
                const float* eb = emb + Mi1*CH;
                double D0 = 0.0, D1 = 0.0;
                for (int c = 0; c < CH; ++c) {
                    double zv = (double)zp[c*49];
                    double f0 = zv - (double)ea[c];
                    double f1 = zv - (double)eb[c];
                    D0 += f0*f0; D1 += f1*f1;
                }
                if (D1 < D0 || (D1 == D0 && Mi1 < Mi0)) win = Mi1;
            }

            float* zqp = out + ZQ_OFF + (long long)b*3136 + hw;
            const float* e0p = emb + win*CH + g*16;
            #pragma unroll
            for (int j = 0; j < 16; ++j) zqp[(g*16 + j)*49] = e0p[j];
        }
    }
}

// ---------------- K2: deconv1 via MFMA (64->32, 7->14) + bias, BN1 stats ------------
// r9 structure; staging now float4-vectorized.
__global__ __launch_bounds__(256) void k2_deconv1(
    const float* __restrict__ zq, const unsigned short* __restrict__ w1f,
    const float* __restrict__ b1, unsigned short* __restrict__ c1cls,
    double* __restrict__ stats)
{
    __shared__ __align__(16) unsigned short x_s[2*81*72]; // [img][r<81][72 bf16] 23.3 KiB
    __shared__ float bs[32], bq[32];

    const int tid = threadIdx.x, wave = tid >> 6, lane = tid & 63;
    const int b0 = blockIdx.x << 1;

    for (int i = tid; i < 2*81*72/2; i += 256) ((unsigned int*)x_s)[i] = 0u;
    if (tid < 32) { bs[tid] = 0.f; bq[tid] = 0.f; }
    __syncthreads();

    {
        const float4* zb4 = (const float4*)(zq + (long long)b0*3136);
        for (int i = tid; i < 1568; i += 256) {
            float4 v = zb4[i];
            float vv[4] = {v.x, v.y, v.z, v.w};
            int base = i << 2;
            #pragma unroll
            for (int j = 0; j < 4; ++j) {
                int idx = base + j;
                int img = idx >= 3136;
                int e = idx - img*3136;
                int c = e / 49, hw = e - c*49;
                int ih = hw / 7, iw = hw - ih*7;
                x_s[img*5832 + ((ih+1)*9 + (iw+1))*72 + c] = f2bf(vv[j]);
            }
        }
    }
    __syncthreads();

    const int cls = wave, ph = cls >> 1, pw = cls & 1;
    bf16x8 wfr[4][2][2];   // [tap][khalf][mtile]
    {
        const uint4* wp = (const uint4*)w1f + (cls*16)*64 + lane;
        #pragma unroll
        for (int tap = 0; tap < 4; ++tap)
            #pragma unroll
            for (int kh2 = 0; kh2 < 2; ++kh2)
                #pragma unroll
                for (int mt = 0; mt < 2; ++mt) {
                    B8 t; t.u = wp[(tap*4 + kh2*2 + mt)*64];
                    wfr[tap][kh2][mt] = t.v;
                }
    }
    float biasv[2][4];
    #pragma unroll
    for (int mt = 0; mt < 2; ++mt)
        #pragma unroll
        for (int rg = 0; rg < 4; ++rg)
            biasv[mt][rg] = b1[mt*16 + ((lane >> 4) << 2) + rg];

    float ts[2][4] = {{0.f}}, tq[2][4] = {{0.f}};
    const int gb = (lane >> 4) << 4;

    for (int nt = 0; nt < 7; ++nt) {
        int m = nt*16 + (lane & 15);
        bool valid = m < 98;
        int mm = valid ? m : 0;
        int img = mm >= 49;
        int px = mm - img*49;
        int a = px / 7, bb = px - a*7;
        f32x4 acc0 = {0.f,0.f,0.f,0.f}, acc1 = {0.f,0.f,0.f,0.f};
        #pragma unroll
        for (int dh = 0; dh < 2; ++dh)
            #pragma unroll
            for (int dw = 0; dw < 2; ++dw) {
                int tap = dh*2 + dw;
                int r = (a + ph - dh + 1)*9 + (bb + pw - dw + 1);
                const char* p = (const char*)x_s + img*11664 + r*144 + gb;
                B8 x0; x0.u = *(const uint4*)p;
                B8 x1; x1.u = *(const uint4*)(p + 64);
                acc0 = __builtin_amdgcn_mfma_f32_16x16x32_bf16(wfr[tap][0][0], x0.v, acc0, 0,0,0);
                acc1 = __builtin_amdgcn_mfma_f32_16x16x32_bf16(wfr[tap][0][1], x0.v, acc1, 0,0,0);
                acc0 = __builtin_amdgcn_mfma_f32_16x16x32_bf16(wfr[tap][1][0], x1.v, acc0, 0,0,0);
                acc1 = __builtin_amdgcn_mfma_f32_16x16x32_bf16(wfr[tap][1][1], x1.v, acc1, 0,0,0);
            }
        if (valid) {
            unsigned short* base = c1cls + (long long)(b0+img)*6272 + cls*1568 + px;
            #pragma unroll
            for (int rg = 0; rg < 4; ++rg) {
                int oc = ((lane >> 4) << 2) + rg;
                float v0 = acc0[rg] + biasv[0][rg];
                float v1 = acc1[rg] + biasv[1][rg];
                base[oc*49]      = f2bf(v0);
                base[(oc+16)*49] = f2bf(v1);
                ts[0][rg] += v0; tq[0][rg] = fmaf(v0, v0, tq[0][rg]);
                ts[1][rg] += v1; tq[1][rg] = fmaf(v1, v1, tq[1][rg]);
            }
        }
    }

    #pragma unroll
    for (int mt = 0; mt < 2; ++mt)
        #pragma unroll
        for (int rg = 0; rg < 4; ++rg) {
            float s = ts[mt][rg], q = tq[mt][rg];
            #pragma unroll
            for (int msk = 1; msk < 16; msk <<= 1) {
                s += __shfl_xor(s, msk);
                q += __shfl_xor(q, msk);
            }
            if ((lane & 15) == 0) {
                int oc = mt*16 + ((lane >> 4) << 2) + rg;
                atomicAdd(&bs[oc], s);
                atomicAdd(&bq[oc], q);
            }
        }
    __syncthreads();
    if (tid < 32) {
        atomicAdd(&stats[tid],      (double)bs[tid]);
        atomicAdd(&stats[32 + tid], (double)bq[tid]);
    }
}

// ---------------- K4: BN1 (from stats, folded) + ReLU, deconv2 via MFMA, BN2 stats ---
// r9 structure; staging now uint4-vectorized (8 bf16 per load).
__global__ __launch_bounds__(256) void k4_deconv2(
    const unsigned short* __restrict__ c1cls, const unsigned short* __restrict__ w2f,
    const float* __restrict__ b2, const float* __restrict__ g1,
    const float* __restrict__ be1, double* stats,
    unsigned short* __restrict__ c2cls)
{
    __shared__ __align__(16) unsigned short x_s[256*40];  // [r<256][40 bf16] 20 KiB
    __shared__ float bnl[64];
    __shared__ float bs[16], bq[16];

    const int tid = threadIdx.x, wave = tid >> 6, lane = tid & 63;
    const int b = blockIdx.x;

    for (int i = tid; i < 256*40/2; i += 256) ((unsigned int*)x_s)[i] = 0u;
    if (tid < 32) {
        const double n = 4096.0*196.0;
        double mean = stats[tid] / n;
        double var  = stats[32 + tid] / n - mean*mean;
        double rstd = 1.0 / sqrt(var + 1e-5);
        double sc   = (double)g1[tid] * rstd;
        bnl[tid]      = (float)sc;
        bnl[32 + tid] = (float)((double)be1[tid] - mean*sc);
    }
    if (tid < 16) { bs[tid] = 0.f; bq[tid] = 0.f; }
    __syncthreads();

    {
        const uint4* cb4 = (const uint4*)(c1cls + (long long)b*6272);
        for (int i = tid; i < 784; i += 256) {
            uint4 v = cb4[i];
            unsigned int w[4] = {v.x, v.y, v.z, v.w};
            int base = i << 3;
            #pragma unroll
            for (int j = 0; j < 8; ++j) {
                unsigned short us = (unsigned short)(w[j >> 1] >> ((j & 1) * 16));
                int idx = base + j;
                int cl = idx / 1568, e = idx - cl*1568;
                int ic = e / 49, pxc = e - ic*49;
                int a = pxc / 7, bb2 = pxc - a*7;
                int ih = 2*a + (cl >> 1), iw = 2*bb2 + (cl & 1);
                float vv = fmaxf(fmaf(bf2f(us), bnl[ic], bnl[32 + ic]), 0.f);
                x_s[((ih+1)*16 + (iw+1))*40 + ic] = f2bf(vv);
            }
        }
    }
    __syncthreads();

    const int cls = wave, ph = cls >> 1, pw = cls & 1;
    bf16x8 wfr[4];
    {
        const uint4* wp = (const uint4*)w2f + (cls*4)*64 + lane;
        #pragma unroll
        for (int tap = 0; tap < 4; ++tap) { B8 t; t.u = wp[tap*64]; wfr[tap] = t.v; }
    }
    float biasv[4];
    #pragma unroll
    for (int rg = 0; rg < 4; ++rg) biasv[rg] = b2[((lane >> 4) << 2) + rg];

    float ts[4] = {0.f}, tq[4] = {0.f};
    unsigned short* c2b = c2cls + (long long)b*12544 + cls*3136;
    const int gb = (lane >> 4) << 4;

    for (int nt = 0; nt < 13; ++nt) {
        int m = nt*16 + (lane & 15);
        bool valid = m < 196;
        int px = valid ? m : 0;
        int a = px / 14, bb = px - a*14;
        f32x4 acc = {0.f,0.f,0.f,0.f};
        #pragma unroll
        for (int dh = 0; dh < 2; ++dh)
            #pragma unroll
            for (int dw = 0; dw < 2; ++dw) {
                int tap = dh*2 + dw;
                int r = (a + ph - dh + 1)*16 + (bb + pw - dw + 1);
                B8 x0; x0.u = *(const uint4*)((const char*)x_s + r*80 + gb);
                acc = __builtin_amdgcn_mfma_f32_16x16x32_bf16(wfr[tap], x0.v, acc, 0,0,0);
            }
        if (valid) {
            unsigned short* base = c2b + px;
            #pragma unroll
            for (int rg = 0; rg < 4; ++rg) {
                int oc = ((lane >> 4) << 2) + rg;
                float v = acc[rg] + biasv[rg];
                base[oc*196] = f2bf(v);
                ts[rg] += v; tq[rg] = fmaf(v, v, tq[rg]);
            }
        }
    }

    #pragma unroll
    for (int rg = 0; rg < 4; ++rg) {
        float s = ts[rg], q = tq[rg];
        #pragma unroll
        for (int msk = 1; msk < 16; msk <<= 1) {
            s += __shfl_xor(s, msk);
            q += __shfl_xor(q, msk);
        }
        if ((lane & 15) == 0) {
            int oc = ((lane >> 4) << 2) + rg;
            atomicAdd(&bs[oc], s);
            atomicAdd(&bq[oc], q);
        }
    }
    __syncthreads();
    if (tid < 16) {
        atomicAdd(&stats[64 + tid], (double)bs[tid]);
        atomicAdd(&stats[80 + tid], (double)bq[tid]);
    }
}

// ---------------- K6: BN2 (from stats, folded) + ReLU, 3x3 conv 16->1, sigmoid ------
// r9 structure; staging now uint-vectorized (2 bf16 per load, same contiguous run).
__global__ __launch_bounds__(256) void k6_conv(
    const unsigned short* __restrict__ c2cls, const float* __restrict__ cw,
    const float* __restrict__ cbias, const float* __restrict__ g2,
    const float* __restrict__ be2, const double* __restrict__ stats,
    float* __restrict__ out)
{
    __shared__ float x_s[9*31*16];      // [9 rows][31 col-slots][16 ch] 17.4 KiB
    __shared__ float w_s[144];          // [khw=9][ic=16]
    __shared__ float bn2[32];

    const int tid  = threadIdx.x;
    const int b    = blockIdx.x >> 2;
    const int qrt  = blockIdx.x & 3;    // output rows [qrt*7, qrt*7+7)
    const int r0   = qrt*7 - 1;         // first staged input row (may be -1)

    for (int i = tid; i < 9*31*16; i += 256) x_s[i] = 0.f;
    if (tid < 144) {
        int ic = tid / 9, khw = tid - ic*9;   // cw is [ic=16][kh][kw]
        w_s[khw*16 + ic] = cw[tid];
    }
    if (tid >= 192 && tid < 208) {
        int c = tid - 192;
        const double n = 4096.0*784.0;
        double mean = stats[64 + c] / n;
        double var  = stats[80 + c] / n - mean*mean;
        double rstd = 1.0 / sqrt(var + 1e-5);
        double sc   = (double)g2[c] * rstd;
        bn2[c]      = (float)sc;
        bn2[16 + c] = (float)((double)be2[c] - mean*sc);
    }
    __syncthreads();

    const unsigned short* cr = c2cls + (long long)b*12544;
    // 2016 uint loads: [c<16][rr<9][iwp<2][j<7]; each uint = px2 pair (2j,2j+1)
    for (int i = tid; i < 2016; i += 256) {
        int c    = i / 126;
        int rem  = i - c*126;
        int rr   = rem / 14;
        int rem2 = rem - rr*14;
        int iwp  = rem2 / 7;
        int j    = rem2 - iwp*7;
        int ih   = r0 + rr;
        if ((unsigned)ih < 28u) {
            int cl = ((ih & 1) << 1) | iwp;
            const unsigned int* p = (const unsigned int*)(cr + cl*3136 + c*196 + (ih >> 1)*14);
            unsigned int u = p[j];
            float v0 = fmaxf(fmaf(bf2f((unsigned short)u),         bn2[c], bn2[16 + c]), 0.f);
            float v1 = fmaxf(fmaf(bf2f((unsigned short)(u >> 16)), bn2[c], bn2[16 + c]), 0.f);
            int iw0 = 4*j + iwp;
            x_s[(rr*31 + iw0 + 1)*16 + c] = v0;
            x_s[(rr*31 + iw0 + 3)*16 + c] = v1;
        }
    }
    __syncthreads();

    const float bias = cbias[0];
    const int px = tid;
    if (px < 196) {
        int ohl = px / 28, ow = px - ohl*28;
        float a0=0.f,a1=0.f,a2=0.f,a3=0.f;
        #pragma unroll
        for (int kh = 0; kh < 3; ++kh) {
            #pragma unroll
            for (int kw = 0; kw < 3; ++kw) {
                const float4* xv = (const float4*)&x_s[((ohl+kh)*31 + ow+kw)*16];
                const float4* wv = (const float4*)&w_s[((kh*3 + kw) << 4)];
                #pragma unroll
                for (int c4 = 0; c4 < 4; ++c4) {
                    float4 xx = xv[c4];
                    float4 ww = wv[c4];
                    a0 = fmaf(xx.x, ww.x, a0);
                    a1 = fmaf(xx.y, ww.y, a1);
                    a2 = fmaf(xx.z, ww.z, a2);
                    a3 = fmaf(xx.w, ww.w, a3);
                }
            }
        }
        float t = ((a0+a1) + (a2+a3)) + bias;
        out[(long long)b*784 + (qrt*7 + ohl)*28 + ow] = 1.f / (1.f + expf(-t));
    }
}

// ---------------- launch ----------------
extern "C" void kernel_launch(void* const* d_in, const int* in_sizes, int n_in,
                              void* d_out, int out_size, void* d_ws, size_t ws_size,
                              hipStream_t stream) {
    const int*   x    = (const int*)d_in[0];
    const float* encW = (const float*)d_in[1];
    const float* emb  = (const float*)d_in[2];
    const float* w1   = (const float*)d_in[3];
    const float* b1   = (const float*)d_in[4];
    const float* g1   = (const float*)d_in[5];
    const float* be1  = (const float*)d_in[6];
    const float* w2   = (const float*)d_in[7];
    const float* b2   = (const float*)d_in[8];
    const float* g2   = (const float*)d_in[9];
    const float* be2  = (const float*)d_in[10];
    const float* cw   = (const float*)d_in[11];
    const float* cb   = (const float*)d_in[12];
    float* out = (float*)d_out;

    char* ws = (char*)d_ws;
    unsigned short* c1cls = (unsigned short*)(ws + WS_C1);
    unsigned short* c2cls = (unsigned short*)(ws + WS_C2);
    double*         stats = (double*)(ws + WS_ST);
    unsigned short* w1f   = (unsigned short*)(ws + WS_WF1);
    unsigned short* w2f   = (unsigned short*)(ws + WS_WF2);
    unsigned short* ef    = (unsigned short*)(ws + WS_EF);
    float*          eeW   = (float*)(ws + WS_EE);

    k_prep<<<256, 256, 0, stream>>>(w1, w2, emb, w1f, w2f, ef, eeW, stats);
    k1_encode<<<2048, 256, 0, stream>>>(x, encW, emb, ef, eeW, out);
    k2_deconv1<<<2048, 256, 0, stream>>>(out + ZQ_OFF, w1f, b1, c1cls, stats);
    k4_deconv2<<<4096, 256, 0, stream>>>(c1cls, w2f, b2, g1, be1, stats, c2cls);
    k6_conv<<<16384, 256, 0, stream>>>(c2cls, cw, cb, g2, be2, stats, out);
}

// Round 12
// 463.535 us; speedup vs baseline: 1.2106x; 1.2106x over previous
//
#include <hip/hip_runtime.h>
#include <hip/hip_bf16.h>
#include <math.h>

// ---------------- problem constants ----------------
#define BATCH   4096
#define CH      64          // latent channels
#define KCB     512         // codebook size

// d_out layout (floats): x_tilde [4096,1,28,28], z_e_x [4096,64,7,7], z_q_x [4096,64,7,7]
#define XT_N    (BATCH*784)
#define ZE_OFF  (XT_N)
#define ZQ_OFF  (XT_N + BATCH*3136)

// workspace layout (bytes) — c1/c2 bf16
#define WS_C1   0
#define WS_C2   51380224ULL
#define WS_ST   154140672ULL            // stats: double sum1[32] sq1[32] sum2[16] sq2[16]
#define WS_WF2  154141824ULL            // w2 MFMA frags bf16: 16 KiB
#define WS_EF   154158208ULL            // codebook hi/lo MFMA frags: 128 KiB
#define WS_EE   154289280ULL            // ee[512] fp32 (fp64-accurate ||e||^2)
#define WS_WF1  WS_C2                   // w1 frags, clobbered later by c2 writes (stream order)

typedef __attribute__((ext_vector_type(8))) __bf16 bf16x8;
typedef __attribute__((ext_vector_type(4))) float f32x4;
union B8 { uint4 u; bf16x8 v; };

__device__ inline unsigned short f2bf(float f) {   // RNE fp32->bf16
    unsigned int u = __float_as_uint(f);
    u = u + 0x7fffu + ((u >> 16) & 1u);
    return (unsigned short)(u >> 16);
}
__device__ inline float bf2f(unsigned short h) {
    return __uint_as_float(((unsigned int)h) << 16);
}

// ---------------- prep: pack weights + codebook into per-lane MFMA fragments --------
// FROZEN. Slot rule shared by A and B: lane l, elem i -> k = kbase + 8*(l>>4) + i.
__global__ void k_prep(const float* __restrict__ w1, const float* __restrict__ w2,
                       const float* __restrict__ emb,
                       unsigned short* __restrict__ w1f, unsigned short* __restrict__ w2f,
                       unsigned short* __restrict__ ef, float* __restrict__ eeW,
                       double* __restrict__ stats) {
    int t = threadIdx.x + blockIdx.x * 256;     // 0..65535
    if (t < 96) stats[t] = 0.0;
    {   // codebook hi/lo fragments
        int i = t & 7, lane = (t >> 3) & 63, frag = t >> 9;       // frag 0..127
        int mt = frag >> 2, khalf = (frag >> 1) & 1, hilo = frag & 1;
        int cw = mt * 16 + (lane & 15);
        int k  = khalf * 32 + ((lane >> 4) << 3) + i;
        float v = emb[(cw << 6) + k];
        unsigned short h = f2bf(v);
        ef[t] = hilo ? f2bf(v - bf2f(h)) : h;
    }
    if (t < 32768) {
        int i = t & 7, lane = (t >> 3) & 63, frag = t >> 9;
        int cls = frag >> 4, tap = (frag >> 2) & 3, khalf = (frag >> 1) & 1, mt = frag & 1;
        int ph = cls >> 1, pw = cls & 1, dh = tap >> 1, dw = tap & 1;
        int kh = (1 - ph) + 2 * dh, kw = (1 - pw) + 2 * dw;
        int oc = mt * 16 + (lane & 15);
        int ic = khalf * 32 + ((lane >> 4) << 3) + i;
        w1f[t] = f2bf(w1[((ic * 32 + oc) << 4) + kh * 4 + kw]);
    }
    if (t < 8192) {
        int i = t & 7, lane = (t >> 3) & 63, frag = t >> 9;   // frag < 16
        int cls = frag >> 2, tap = frag & 3;
        int ph = cls >> 1, pw = cls & 1, dh = tap >> 1, dw = tap & 1;
        int kh = (1 - ph) + 2 * dh, kw = (1 - pw) + 2 * dw;
        int oc = lane & 15;
        int ic = ((lane >> 4) << 3) + i;
        w2f[t] = f2bf(w2[((ic * 16 + oc) << 4) + kh * 4 + kw]);
    }
    if (t < KCB) {
        double s = 0.0;
        const float* e = emb + (t << 6);
        for (int c = 0; c < CH; ++c) s += (double)e[c] * (double)e[c];
        eeW[t] = (float)s;
    }
}

// ---------------- K1: gather + VQ argmin via split-bf16 MFMA + z_e_x/z_q_x ----------
// REVERTED to r10 (single top-2 chain in registers — no runtime-indexed arrays,
// rule #20: the r11 parity split put d0/k0 in scratch and cost +88 us).
__global__ __launch_bounds__(256) void k1_encode(
    const int* __restrict__ xidx, const float* __restrict__ encW,
    const float* __restrict__ emb, const unsigned short* __restrict__ ef,
    const float* __restrict__ eeW, float* __restrict__ out)
{
    __shared__ __align__(16) unsigned short zh_s[98*72];
    __shared__ __align__(16) unsigned short zl_s[98*72];
    __shared__ float ee_s[KCB];

    const int tid = threadIdx.x, wave = tid >> 6, lane = tid & 63;
    const int b0 = blockIdx.x << 1;

    for (int k = tid; k < KCB; k += 256) ee_s[k] = eeW[k];

    {
        const long long r0 = xidx[b0], r1 = xidx[b0 + 1];
        const float4* src0 = (const float4*)(encW + r0*3136);
        const float4* src1 = (const float4*)(encW + r1*3136);
        float4* ze = (float4*)(out + ZE_OFF + (long long)b0*3136);
        for (int i = tid; i < 1568; i += 256) {
            float4 v = (i < 784) ? src0[i] : src1[i - 784];
            ze[i] = v;
            float vv[4] = {v.x, v.y, v.z, v.w};
            int base = i << 2;
            #pragma unroll
            for (int j = 0; j < 4; ++j) {
                int idx = base + j;               // 0..6271 over [img][c][hw]
                int img = idx >= 3136;
                int e   = idx - img*3136;
                int c   = e / 49, hw = e - c*49;
                int pos = img*49 + hw;
                unsigned short hb = f2bf(vv[j]);
                zh_s[pos*72 + c] = hb;
                zl_s[pos*72 + c] = f2bf(vv[j] - bf2f(hb));
            }
        }
    }
    __syncthreads();

    const int col = lane & 15, g = lane >> 4;
    B8 Bh[2][2], Bl[2][2];
    #pragma unroll
    for (int t2 = 0; t2 < 2; ++t2) {
        int pos  = (wave*2 + t2)*16 + col;
        int posc = pos < 98 ? pos : 97;
        #pragma unroll
        for (int kh = 0; kh < 2; ++kh) {
            Bh[t2][kh].u = *(const uint4*)(zh_s + posc*72 + kh*32 + g*8);
            Bl[t2][kh].u = *(const uint4*)(zl_s + posc*72 + kh*32 + g*8);
        }
    }

    float d0[2] = {3.4e38f, 3.4e38f}, d1[2] = {3.4e38f, 3.4e38f};
    int   k0[2] = {0, 0},             k1i[2] = {1, 1};

    const uint4* ap = (const uint4*)ef + lane;
    uint4 A0 = ap[0*64], A1 = ap[1*64], A2 = ap[2*64], A3 = ap[3*64];

    for (int mt = 0; mt < 32; ++mt) {
        B8 Ah0, Al0, Ah1, Al1;
        Ah0.u = A0; Al0.u = A1; Ah1.u = A2; Al1.u = A3;
        if (mt < 31) {
            const uint4* np = ap + (mt+1)*256;
            A0 = np[0]; A1 = np[64]; A2 = np[128]; A3 = np[192];
        }
        const float4 eev = *(const float4*)&ee_s[mt*16 + (g << 2)];
        #pragma unroll
        for (int t2 = 0; t2 < 2; ++t2) {
            f32x4 acc = {eev.x*-0.5f, eev.y*-0.5f, eev.z*-0.5f, eev.w*-0.5f};
            acc = __builtin_amdgcn_mfma_f32_16x16x32_bf16(Ah0.v, Bh[t2][0].v, acc, 0,0,0);
            acc = __builtin_amdgcn_mfma_f32_16x16x32_bf16(Ah1.v, Bh[t2][1].v, acc, 0,0,0);
            acc = __builtin_amdgcn_mfma_f32_16x16x32_bf16(Ah0.v, Bl[t2][0].v, acc, 0,0,0);
            acc = __builtin_amdgcn_mfma_f32_16x16x32_bf16(Ah1.v, Bl[t2][1].v, acc, 0,0,0);
            acc = __builtin_amdgcn_mfma_f32_16x16x32_bf16(Al0.v, Bh[t2][0].v, acc, 0,0,0);
            acc = __builtin_amdgcn_mfma_f32_16x16x32_bf16(Al1.v, Bh[t2][1].v, acc, 0,0,0);
            acc = __builtin_amdgcn_mfma_f32_16x16x32_bf16(Al0.v, Bl[t2][0].v, acc, 0,0,0);
            acc = __builtin_amdgcn_mfma_f32_16x16x32_bf16(Al1.v, Bl[t2][1].v, acc, 0,0,0);
            #pragma unroll
            for (int rg = 0; rg < 4; ++rg) {
                float s = -2.f * acc[rg];
                int  cw = mt*16 + (g << 2) + rg;
                if (s < d0[t2] || (s == d0[t2] && cw < k0[t2])) {
                    d1[t2] = d0[t2]; k1i[t2] = k0[t2]; d0[t2] = s; k0[t2] = cw;
                } else if (s < d1[t2] || (s == d1[t2] && cw < k1i[t2])) {
                    d1[t2] = s; k1i[t2] = cw;
                }
            }
        }
    }

    #pragma unroll
    for (int t2 = 0; t2 < 2; ++t2) {
        #pragma unroll
        for (int msk = 16; msk <= 32; msk <<= 1) {
            float e0 = __shfl_xor(d0[t2], msk), e1 = __shfl_xor(d1[t2], msk);
            int   j0 = __shfl_xor(k0[t2], msk), j1 = __shfl_xor(k1i[t2], msk);
            if (e0 < d0[t2] || (e0 == d0[t2] && j0 < k0[t2])) {
                if (d0[t2] < e1 || (d0[t2] == e1 && k0[t2] < j1)) { d1[t2] = d0[t2]; k1i[t2] = k0[t2]; }
                else                                              { d1[t2] = e1;     k1i[t2] = j1;     }
                d0[t2] = e0; k0[t2] = j0;
            } else {
                if (e0 < d1[t2] || (e0 == d1[t2] && j0 < k1i[t2])) { d1[t2] = e0; k1i[t2] = j0; }
            }
        }

        const int pos = (wave*2 + t2)*16 + col;
        if (pos < 98) {
            const int img = pos >= 49;
            const int b   = b0 + img;
            const int hw  = pos - img*49;
            int win = k0[t2];

            // fp64 refine of near-ties from true fp32 z (engages rarely at 5e-6)
            if (d1[t2] - d0[t2] < 5e-6f) {
                const float* zp = out + ZE_OFF + (long long)b*3136 + hw;
                const float* ea = emb + k0[t2]*CH;
                const float* eb = emb + k1i[t2]*CH;
                double D0 = 0.0, D1 = 0.0;
                for (int c = 0; c < CH; ++c) {
                    double zv = (double)zp[c*49];
                    double f0 = zv - (double)ea[c];
                    double f1 = zv - (double)eb[c];
                    D0 += f0*f0; D1 += f1*f1;
                }
                if (D1 < D0 || (D1 == D0 && k1i[t2] < k0[t2])) win = k1i[t2];
            }

            float* zqp = out + ZQ_OFF + (long long)b*3136 + hw;
            const float* e0p = emb + win*CH + g*16;
            #pragma unroll
            for (int j = 0; j < 16; ++j) zqp[(g*16 + j)*49] = e0p[j];
        }
    }
}

// ---------------- K2: deconv1 via MFMA (64->32, 7->14) + bias, BN1 stats ------------
// r9 structure; float4-vectorized staging (kept from r11).
__global__ __launch_bounds__(256) void k2_deconv1(
    const float* __restrict__ zq, const unsigned short* __restrict__ w1f,
    const float* __restrict__ b1, unsigned short* __restrict__ c1cls,
    double* __restrict__ stats)
{
    __shared__ __align__(16) unsigned short x_s[2*81*72]; // [img][r<81][72 bf16] 23.3 KiB
    __shared__ float bs[32], bq[32];

    const int tid = threadIdx.x, wave = tid >> 6, lane = tid & 63;
    const int b0 = blockIdx.x << 1;

    for (int i = tid; i < 2*81*72/2; i += 256) ((unsigned int*)x_s)[i] = 0u;
    if (tid < 32) { bs[tid] = 0.f; bq[tid] = 0.f; }
    __syncthreads();

    {
        const float4* zb4 = (const float4*)(zq + (long long)b0*3136);
        for (int i = tid; i < 1568; i += 256) {
            float4 v = zb4[i];
            float vv[4] = {v.x, v.y, v.z, v.w};
            int base = i << 2;
            #pragma unroll
            for (int j = 0; j < 4; ++j) {
                int idx = base + j;
                int img = idx >= 3136;
                int e = idx - img*3136;
                int c = e / 49, hw = e - c*49;
                int ih = hw / 7, iw = hw - ih*7;
                x_s[img*5832 + ((ih+1)*9 + (iw+1))*72 + c] = f2bf(vv[j]);
            }
        }
    }
    __syncthreads();

    const int cls = wave, ph = cls >> 1, pw = cls & 1;
    bf16x8 wfr[4][2][2];   // [tap][khalf][mtile]
    {
        const uint4* wp = (const uint4*)w1f + (cls*16)*64 + lane;
        #pragma unroll
        for (int tap = 0; tap < 4; ++tap)
            #pragma unroll
            for (int kh2 = 0; kh2 < 2; ++kh2)
                #pragma unroll
                for (int mt = 0; mt < 2; ++mt) {
                    B8 t; t.u = wp[(tap*4 + kh2*2 + mt)*64];
                    wfr[tap][kh2][mt] = t.v;
                }
    }
    float biasv[2][4];
    #pragma unroll
    for (int mt = 0; mt < 2; ++mt)
        #pragma unroll
        for (int rg = 0; rg < 4; ++rg)
            biasv[mt][rg] = b1[mt*16 + ((lane >> 4) << 2) + rg];

    float ts[2][4] = {{0.f}}, tq[2][4] = {{0.f}};
    const int gb = (lane >> 4) << 4;

    for (int nt = 0; nt < 7; ++nt) {
        int m = nt*16 + (lane & 15);
        bool valid = m < 98;
        int mm = valid ? m : 0;
        int img = mm >= 49;
        int px = mm - img*49;
        int a = px / 7, bb = px - a*7;
        f32x4 acc0 = {0.f,0.f,0.f,0.f}, acc1 = {0.f,0.f,0.f,0.f};
        #pragma unroll
        for (int dh = 0; dh < 2; ++dh)
            #pragma unroll
            for (int dw = 0; dw < 2; ++dw) {
                int tap = dh*2 + dw;
                int r = (a + ph - dh + 1)*9 + (bb + pw - dw + 1);
                const char* p = (const char*)x_s + img*11664 + r*144 + gb;
                B8 x0; x0.u = *(const uint4*)p;
                B8 x1; x1.u = *(const uint4*)(p + 64);
                acc0 = __builtin_amdgcn_mfma_f32_16x16x32_bf16(wfr[tap][0][0], x0.v, acc0, 0,0,0);
                acc1 = __builtin_amdgcn_mfma_f32_16x16x32_bf16(wfr[tap][0][1], x0.v, acc1, 0,0,0);
                acc0 = __builtin_amdgcn_mfma_f32_16x16x32_bf16(wfr[tap][1][0], x1.v, acc0, 0,0,0);
                acc1 = __builtin_amdgcn_mfma_f32_16x16x32_bf16(wfr[tap][1][1], x1.v, acc1, 0,0,0);
            }
        if (valid) {
            unsigned short* base = c1cls + (long long)(b0+img)*6272 + cls*1568 + px;
            #pragma unroll
            for (int rg = 0; rg < 4; ++rg) {
                int oc = ((lane >> 4) << 2) + rg;
                float v0 = acc0[rg] + biasv[0][rg];
                float v1 = acc1[rg] + biasv[1][rg];
                base[oc*49]      = f2bf(v0);
                base[(oc+16)*49] = f2bf(v1);
                ts[0][rg] += v0; tq[0][rg] = fmaf(v0, v0, tq[0][rg]);
                ts[1][rg] += v1; tq[1][rg] = fmaf(v1, v1, tq[1][rg]);
            }
        }
    }

    #pragma unroll
    for (int mt = 0; mt < 2; ++mt)
        #pragma unroll
        for (int rg = 0; rg < 4; ++rg) {
            float s = ts[mt][rg], q = tq[mt][rg];
            #pragma unroll
            for (int msk = 1; msk < 16; msk <<= 1) {
                s += __shfl_xor(s, msk);
                q += __shfl_xor(q, msk);
            }
            if ((lane & 15) == 0) {
                int oc = mt*16 + ((lane >> 4) << 2) + rg;
                atomicAdd(&bs[oc], s);
                atomicAdd(&bq[oc], q);
            }
        }
    __syncthreads();
    if (tid < 32) {
        atomicAdd(&stats[tid],      (double)bs[tid]);
        atomicAdd(&stats[32 + tid], (double)bq[tid]);
    }
}

// ---------------- K4: BN1 (from stats, folded) + ReLU, deconv2 via MFMA, BN2 stats ---
// r9 structure; uint4-vectorized staging (kept from r11).
__global__ __launch_bounds__(256) void k4_deconv2(
    const unsigned short* __restrict__ c1cls, const unsigned short* __restrict__ w2f,
    const float* __restrict__ b2, const float* __restrict__ g1,
    const float* __restrict__ be1, double* stats,
    unsigned short* __restrict__ c2cls)
{
    __shared__ __align__(16) unsigned short x_s[256*40];  // [r<256][40 bf16] 20 KiB
    __shared__ float bnl[64];
    __shared__ float bs[16], bq[16];

    const int tid = threadIdx.x, wave = tid >> 6, lane = tid & 63;
    const int b = blockIdx.x;

    for (int i = tid; i < 256*40/2; i += 256) ((unsigned int*)x_s)[i] = 0u;
    if (tid < 32) {
        const double n = 4096.0*196.0;
        double mean = stats[tid] / n;
        double var  = stats[32 + tid] / n - mean*mean;
        double rstd = 1.0 / sqrt(var + 1e-5);
        double sc   = (double)g1[tid] * rstd;
        bnl[tid]      = (float)sc;
        bnl[32 + tid] = (float)((double)be1[tid] - mean*sc);
    }
    if (tid < 16) { bs[tid] = 0.f; bq[tid] = 0.f; }
    __syncthreads();

    {
        const uint4* cb4 = (const uint4*)(c1cls + (long long)b*6272);
        for (int i = tid; i < 784; i += 256) {
            uint4 v = cb4[i];
            unsigned int w[4] = {v.x, v.y, v.z, v.w};
            int base = i << 3;
            #pragma unroll
            for (int j = 0; j < 8; ++j) {
                unsigned short us = (unsigned short)(w[j >> 1] >> ((j & 1) * 16));
                int idx = base + j;
                int cl = idx / 1568, e = idx - cl*1568;
                int ic = e / 49, pxc = e - ic*49;
                int a = pxc / 7, bb2 = pxc - a*7;
                int ih = 2*a + (cl >> 1), iw = 2*bb2 + (cl & 1);
                float vv = fmaxf(fmaf(bf2f(us), bnl[ic], bnl[32 + ic]), 0.f);
                x_s[((ih+1)*16 + (iw+1))*40 + ic] = f2bf(vv);
            }
        }
    }
    __syncthreads();

    const int cls = wave, ph = cls >> 1, pw = cls & 1;
    bf16x8 wfr[4];
    {
        const uint4* wp = (const uint4*)w2f + (cls*4)*64 + lane;
        #pragma unroll
        for (int tap = 0; tap < 4; ++tap) { B8 t; t.u = wp[tap*64]; wfr[tap] = t.v; }
    }
    float biasv[4];
    #pragma unroll
    for (int rg = 0; rg < 4; ++rg) biasv[rg] = b2[((lane >> 4) << 2) + rg];

    float ts[4] = {0.f}, tq[4] = {0.f};
    unsigned short* c2b = c2cls + (long long)b*12544 + cls*3136;
    const int gb = (lane >> 4) << 4;

    for (int nt = 0; nt < 13; ++nt) {
        int m = nt*16 + (lane & 15);
        bool valid = m < 196;
        int px = valid ? m : 0;
        int a = px / 14, bb = px - a*14;
        f32x4 acc = {0.f,0.f,0.f,0.f};
        #pragma unroll
        for (int dh = 0; dh < 2; ++dh)
            #pragma unroll
            for (int dw = 0; dw < 2; ++dw) {
                int tap = dh*2 + dw;
                int r = (a + ph - dh + 1)*16 + (bb + pw - dw + 1);
                B8 x0; x0.u = *(const uint4*)((const char*)x_s + r*80 + gb);
                acc = __builtin_amdgcn_mfma_f32_16x16x32_bf16(wfr[tap], x0.v, acc, 0,0,0);
            }
        if (valid) {
            unsigned short* base = c2b + px;
            #pragma unroll
            for (int rg = 0; rg < 4; ++rg) {
                int oc = ((lane >> 4) << 2) + rg;
                float v = acc[rg] + biasv[rg];
                base[oc*196] = f2bf(v);
                ts[rg] += v; tq[rg] = fmaf(v, v, tq[rg]);
            }
        }
    }

    #pragma unroll
    for (int rg = 0; rg < 4; ++rg) {
        float s = ts[rg], q = tq[rg];
        #pragma unroll
        for (int msk = 1; msk < 16; msk <<= 1) {
            s += __shfl_xor(s, msk);
            q += __shfl_xor(q, msk);
        }
        if ((lane & 15) == 0) {
            int oc = ((lane >> 4) << 2) + rg;
            atomicAdd(&bs[oc], s);
            atomicAdd(&bq[oc], q);
        }
    }
    __syncthreads();
    if (tid < 16) {
        atomicAdd(&stats[64 + tid], (double)bs[tid]);
        atomicAdd(&stats[80 + tid], (double)bq[tid]);
    }
}

// ---------------- K6: BN2 (from stats, folded) + ReLU, 3x3 conv 16->1, sigmoid ------
// r9 structure; uint-vectorized staging (kept from r11).
__global__ __launch_bounds__(256) void k6_conv(
    const unsigned short* __restrict__ c2cls, const float* __restrict__ cw,
    const float* __restrict__ cbias, const float* __restrict__ g2,
    const float* __restrict__ be2, const double* __restrict__ stats,
    float* __restrict__ out)
{
    __shared__ float x_s[9*31*16];      // [9 rows][31 col-slots][16 ch] 17.4 KiB
    __shared__ float w_s[144];          // [khw=9][ic=16]
    __shared__ float bn2[32];

    const int tid  = threadIdx.x;
    const int b    = blockIdx.x >> 2;
    const int qrt  = blockIdx.x & 3;    // output rows [qrt*7, qrt*7+7)
    const int r0   = qrt*7 - 1;         // first staged input row (may be -1)

    for (int i = tid; i < 9*31*16; i += 256) x_s[i] = 0.f;
    if (tid < 144) {
        int ic = tid / 9, khw = tid - ic*9;   // cw is [ic=16][kh][kw]
        w_s[khw*16 + ic] = cw[tid];
    }
    if (tid >= 192 && tid < 208) {
        int c = tid - 192;
        const double n = 4096.0*784.0;
        double mean = stats[64 + c] / n;
        double var  = stats[80 + c] / n - mean*mean;
        double rstd = 1.0 / sqrt(var + 1e-5);
        double sc   = (double)g2[c] * rstd;
        bn2[c]      = (float)sc;
        bn2[16 + c] = (float)((double)be2[c] - mean*sc);
    }
    __syncthreads();

    const unsigned short* cr = c2cls + (long long)b*12544;
    // 2016 uint loads: [c<16][rr<9][iwp<2][j<7]; each uint = px2 pair (2j,2j+1)
    for (int i = tid; i < 2016; i += 256) {
        int c    = i / 126;
        int rem  = i - c*126;
        int rr   = rem / 14;
        int rem2 = rem - rr*14;
        int iwp  = rem2 / 7;
        int j    = rem2 - iwp*7;
        int ih   = r0 + rr;
        if ((unsigned)ih < 28u) {
            int cl = ((ih & 1) << 1) | iwp;
            const unsigned int* p = (const unsigned int*)(cr + cl*3136 + c*196 + (ih >> 1)*14);
            unsigned int u = p[j];
            float v0 = fmaxf(fmaf(bf2f((unsigned short)u),         bn2[c], bn2[16 + c]), 0.f);
            float v1 = fmaxf(fmaf(bf2f((unsigned short)(u >> 16)), bn2[c], bn2[16 + c]), 0.f);
            int iw0 = 4*j + iwp;
            x_s[(rr*31 + iw0 + 1)*16 + c] = v0;
            x_s[(rr*31 + iw0 + 3)*16 + c] = v1;
        }
    }
    __syncthreads();

    const float bias = cbias[0];
    const int px = tid;
    if (px < 196) {
        int ohl = px / 28, ow = px - ohl*28;
        float a0=0.f,a1=0.f,a2=0.f,a3=0.f;
        #pragma unroll
        for (int kh = 0; kh < 3; ++kh) {
            #pragma unroll
            for (int kw = 0; kw < 3; ++kw) {
                const float4* xv = (const float4*)&x_s[((ohl+kh)*31 + ow+kw)*16];
                const float4* wv = (const float4*)&w_s[((kh*3 + kw) << 4)];
                #pragma unroll
                for (int c4 = 0; c4 < 4; ++c4) {
                    float4 xx = xv[c4];
                    float4 ww = wv[c4];
                    a0 = fmaf(xx.x, ww.x, a0);
                    a1 = fmaf(xx.y, ww.y, a1);
                    a2 = fmaf(xx.z, ww.z, a2);
                    a3 = fmaf(xx.w, ww.w, a3);
                }
            }
        }
        float t = ((a0+a1) + (a2+a3)) + bias;
        out[(long long)b*784 + (qrt*7 + ohl)*28 + ow] = 1.f / (1.f + expf(-t));
    }
}

// ---------------- launch ----------------
extern "C" void kernel_launch(void* const* d_in, const int* in_sizes, int n_in,
                              void* d_out, int out_size, void* d_ws, size_t ws_size,
                              hipStream_t stream) {
    const int*   x    = (const int*)d_in[0];
    const float* encW = (const float*)d_in[1];
    const float* emb  = (const float*)d_in[2];
    const float* w1   = (const float*)d_in[3];
    const float* b1   = (const float*)d_in[4];
    const float* g1   = (const float*)d_in[5];
    const float* be1  = (const float*)d_in[6];
    const float* w2   = (const float*)d_in[7];
    const float* b2   = (const float*)d_in[8];
    const float* g2   = (const float*)d_in[9];
    const float* be2  = (const float*)d_in[10];
    const float* cw   = (const float*)d_in[11];
    const float* cb   = (const float*)d_in[12];
    float* out = (float*)d_out;

    char* ws = (char*)d_ws;
    unsigned short* c1cls = (unsigned short*)(ws + WS_C1);
    unsigned short* c2cls = (unsigned short*)(ws + WS_C2);
    double*         stats = (double*)(ws + WS_ST);
    unsigned short* w1f   = (unsigned short*)(ws + WS_WF1);
    unsigned short* w2f   = (unsigned short*)(ws + WS_WF2);
    unsigned short* ef    = (unsigned short*)(ws + WS_EF);
    float*          eeW   = (float*)(ws + WS_EE);

    k_prep<<<256, 256, 0, stream>>>(w1, w2, emb, w1f, w2f, ef, eeW, stats);
    k1_encode<<<2048, 256, 0, stream>>>(x, encW, emb, ef, eeW, out);
    k2_deconv1<<<2048, 256, 0, stream>>>(out + ZQ_OFF, w1f, b1, c1cls, stats);
    k4_deconv2<<<4096, 256, 0, stream>>>(c1cls, w2f, b2, g1, be1, stats, c2cls);
    k6_conv<<<16384, 256, 0, stream>>>(c2cls, cw, cb, g2, be2, stats, out);
}